// Round 2
// baseline (735.046 us; speedup 1.0000x reference)
//
#include <hip/hip_runtime.h>

// fTN_NNiso: batched PEPS amplitude with NN-perturbed isometries.
// Shapes: Lx=Ly=6, D=4, CHI=16, H=64, PROJ_LEN=51200, BATCH=1024.
// One block per sample; boundary-MPS column sweep entirely in LDS.
// Reassociated contraction order: (Ms . P) first (halves FLOPs vs reference
// order), then A, then Q.
// peps strides (shape 6,6,4,4,4,4,2): r:3072 c:512 l:128 rb:32 a:8 b:2 p:1

constexpr int   kLy     = 6;
constexpr int   kNSites = 36;
constexpr int   kProj   = 51200;
constexpr float kEta    = 0.001f;

__global__ __launch_bounds__(256, 2)
void tn_amp(const int* __restrict__ x,
            const float* __restrict__ peps,
            const float* __restrict__ base_proj,
            const float* __restrict__ W1,
            const float* __restrict__ b1,
            const float* __restrict__ W2,
            const float* __restrict__ b2,
            float* __restrict__ out,
            int batch)
{
    const int s   = blockIdx.x;
    if (s >= batch) return;
    const int tid = threadIdx.x;

    __shared__ float h[64];
    __shared__ float Ms[6 * 1024];     // [r][u*64 + d*4 + rb], u<16, d<16, rb<4
    __shared__ float bond[2][2048];    // ping-pong vec chunks: [0:1024]=P(64x16), [1024:2048]=Q(16x64)
    __shared__ float A_lds[256];       // [l*64 + rb*16 + a*4 + b]
    __shared__ float MoldP[4096];      // [((u*4 + l)*4 + b)*16 + cc]
    __shared__ float M2s[4096];        // [(ua*DN + dn)*4 + rb]
    __shared__ float vbuf[2][16];

    // ---- h = relu(x @ W1 + b1) ----
    if (tid < 64) {
        float acc = b1[tid];
        for (int i = 0; i < kNSites; ++i) {
            float xv = (float)x[s * kNSites + i];
            acc = fmaf(xv, W1[i * 64 + tid], acc);
        }
        h[tid] = fmaxf(acc, 0.0f);
    }

    // ---- init boundary MPS from column 0 ----
    // Ms[r][u][d][rb] = peps[r, 0, l=0, rb, a=u, b=d, p] zero-padded to (16,16,4)
    for (int idx = tid; idx < 6 * 1024; idx += 256) {
        int r   = idx >> 10;
        int rem = idx & 1023;
        int u = rem >> 6, d = (rem >> 2) & 15, rb = rem & 3;
        int a_dim = (r == 0) ? 1 : 4;
        int b_dim = (r == 5) ? 1 : 4;
        float v = 0.0f;
        if (u < a_dim && d < b_dim) {
            int p = x[s * kNSites + r * kLy + 0];
            v = peps[r * 3072 + rb * 32 + u * 8 + d * 2 + p];
        }
        Ms[idx] = v;
    }
    __syncthreads();

    // ---- column sweep ----
    for (int c = 1; c < 6; ++c) {
        const int rb_dim = (c == 5) ? 1 : 4;
        const int rb_sh  = (c == 5) ? 0 : 2;
        for (int r = 0; r < 6; ++r) {
            const int cur = r & 1;

            // -- generate bond (c-1, r): 2048 floats of vec --
            if (r <= 4) {
                const int goff = ((c - 1) * 5 + r) * 2048;
                const int j0   = tid * 8;
                float acc[8];
#pragma unroll
                for (int i = 0; i < 8; ++i) acc[i] = 0.0f;
                const float* wbase = W2 + goff + j0;
                for (int k = 0; k < 64; ++k) {
                    float hk = h[k];
                    const float4* wp = reinterpret_cast<const float4*>(wbase + (size_t)k * kProj);
                    float4 wa = wp[0];
                    float4 wb = wp[1];
                    acc[0] = fmaf(hk, wa.x, acc[0]);
                    acc[1] = fmaf(hk, wa.y, acc[1]);
                    acc[2] = fmaf(hk, wa.z, acc[2]);
                    acc[3] = fmaf(hk, wa.w, acc[3]);
                    acc[4] = fmaf(hk, wb.x, acc[4]);
                    acc[5] = fmaf(hk, wb.y, acc[5]);
                    acc[6] = fmaf(hk, wb.z, acc[6]);
                    acc[7] = fmaf(hk, wb.w, acc[7]);
                }
#pragma unroll
                for (int i = 0; i < 8; ++i) {
                    int g = goff + j0 + i;
                    bond[cur][j0 + i] = base_proj[g] + kEta * (b2[g] + acc[i]);
                }
            }

            // -- load site tensor A[l][rb][a][b] (invalid slots zeroed) --
            {
                int l = tid >> 6, rb = (tid >> 4) & 3, a = (tid >> 2) & 3, b = tid & 3;
                int a_dim = (r == 0) ? 1 : 4;
                int b_dim = (r == 5) ? 1 : 4;
                float v = 0.0f;
                if (rb < rb_dim && a < a_dim && b < b_dim) {
                    int p = x[s * kNSites + r * kLy + c];
                    v = peps[r * 3072 + c * 512 + l * 128 + rb * 32 + a * 8 + b * 2 + p];
                }
                A_lds[tid] = v;
            }
            __syncthreads();

            const int u0    = (r == 0) ? 1 : 16;
            const int a_sh  = (r == 0) ? 0 : 2;
            const int a_dim = (r == 0) ? 1 : 4;
            const float* Pb = bond[cur];            // P: [db*16 + cc]
            const float* Qb = bond[cur ^ 1] + 1024; // Q: [cq*64 + ua]

            if (r < 5) {
                // Phase 1: MoldP[u,l,b,cc] = sum_d Ms[r][u,d,l] * P[(d*4+b),cc]
                const int n1 = u0 * 4 * 4 * 16;
                for (int idx = tid; idx < n1; idx += 256) {
                    int cc = idx & 15, b = (idx >> 4) & 3, l = (idx >> 6) & 3, u = idx >> 8;
                    const float* mrow = &Ms[r * 1024 + u * 64 + l];
                    float accv = 0.0f;
#pragma unroll
                    for (int d = 0; d < 16; ++d)
                        accv = fmaf(mrow[d * 4], Pb[(d * 4 + b) * 16 + cc], accv);
                    MoldP[idx] = accv;
                }
                __syncthreads();
                // Phase 2: M2[ua,cc,rb] = sum_{l,b} MoldP[u,l,b,cc] * A[l,rb,a,b]
                const int UA = u0 * a_dim;
                const int n2 = UA * 16 * rb_dim;
                for (int idx = tid; idx < n2; idx += 256) {
                    int rb = idx & (rb_dim - 1);
                    int t  = idx >> rb_sh;
                    int cc = t & 15;
                    int ua = t >> 4;
                    int u = ua >> a_sh, a = ua & (a_dim - 1);
                    float accv = 0.0f;
#pragma unroll
                    for (int l = 0; l < 4; ++l)
#pragma unroll
                        for (int b = 0; b < 4; ++b)
                            accv = fmaf(MoldP[((u * 4 + l) * 4 + b) * 16 + cc],
                                        A_lds[l * 64 + rb * 16 + a * 4 + b], accv);
                    M2s[(ua * 16 + cc) * 4 + rb] = accv;
                }
            } else {
                // r == 5 (no P, d-bond is 1): M2[ua,rb] = sum_l Ms[5][u,0,l] * A[l,rb,a,0]
                const int n2 = 64 * rb_dim;
                for (int idx = tid; idx < n2; idx += 256) {
                    int rb = idx & (rb_dim - 1);
                    int ua = idx >> rb_sh;
                    int u = ua >> 2, a = ua & 3;
                    float accv = 0.0f;
#pragma unroll
                    for (int l = 0; l < 4; ++l)
                        accv = fmaf(Ms[5 * 1024 + u * 64 + l],
                                    A_lds[l * 64 + rb * 16 + a * 4], accv);
                    M2s[ua * 4 + rb] = accv;
                }
            }
            __syncthreads();

            const int DN    = (r < 5) ? 16 : 1;
            const int dn_sh = (r < 5) ? 4 : 0;
            if (r > 0) {
                // Phase 3: Ms[r][cq,dn,rb] = sum_ua Q[cq,ua] * M2[ua,dn,rb]
                const int n3 = 16 * DN * rb_dim;
                for (int idx = tid; idx < n3; idx += 256) {
                    int rb = idx & (rb_dim - 1);
                    int t  = idx >> rb_sh;
                    int dn = t & (DN - 1);
                    int cq = t >> dn_sh;
                    float accv = 0.0f;
#pragma unroll
                    for (int ua = 0; ua < 64; ++ua)
                        accv = fmaf(Qb[cq * 64 + ua], M2s[(ua * DN + dn) * 4 + rb], accv);
                    Ms[r * 1024 + cq * 64 + dn * 4 + rb] = accv;
                }
            } else {
                // r == 0: ua-dim is 1, no Q; copy M2 into Ms[0]
                const int n3 = 16 * rb_dim;
                for (int idx = tid; idx < n3; idx += 256) {
                    int rb = idx & (rb_dim - 1);
                    int dn = idx >> rb_sh;
                    Ms[dn * 4 + rb] = M2s[dn * 4 + rb];
                }
            }
            __syncthreads();
        }
    }

    // ---- final 1D chain contraction (rb index 0 after last column) ----
    if (tid < 16) vbuf[0][tid] = Ms[0 * 1024 + tid * 4 + 0];
    __syncthreads();
    for (int r = 1; r < 5; ++r) {
        if (tid < 16) {
            float accv = 0.0f;
            for (int u = 0; u < 16; ++u)
                accv = fmaf(vbuf[(r - 1) & 1][u], Ms[r * 1024 + u * 64 + tid * 4 + 0], accv);
            vbuf[r & 1][tid] = accv;
        }
        __syncthreads();
    }
    if (tid == 0) {
        float accv = 0.0f;
        for (int u = 0; u < 16; ++u)
            accv = fmaf(vbuf[0][u], Ms[5 * 1024 + u * 64 + 0], accv);
        out[s] = accv;
    }
}

extern "C" void kernel_launch(void* const* d_in, const int* in_sizes, int n_in,
                              void* d_out, int out_size, void* d_ws, size_t ws_size,
                              hipStream_t stream) {
    const int*   x         = (const int*)d_in[0];
    const float* peps      = (const float*)d_in[1];
    const float* base_proj = (const float*)d_in[2];
    const float* W1        = (const float*)d_in[3];
    const float* b1        = (const float*)d_in[4];
    const float* W2        = (const float*)d_in[5];
    const float* b2        = (const float*)d_in[6];
    float*       out       = (float*)d_out;

    const int batch = in_sizes[0] / kNSites;
    hipLaunchKernelGGL(tn_amp, dim3(batch), dim3(256), 0, stream,
                       x, peps, base_proj, W1, b1, W2, b2, out, batch);
}

// Round 3
// 411.495 us; speedup vs baseline: 1.7863x; 1.7863x over previous
//
#include <hip/hip_runtime.h>

// fTN_NNiso: batched PEPS amplitude with NN-perturbed isometries.
// Lx=Ly=6, D=4, CHI=16, H=64, PROJ_LEN=51200, BATCH=1024.
// G=4 samples per block (512 threads, 1 block/CU): one W2 read serves 4
// samples' bond matvecs -> 4x less L2/L3 traffic (the round-2 bottleneck).
// Register-tiled contraction phases; conflict-aware LDS strides.
// peps strides (6,6,4,4,4,4,2): r:3072 c:512 l:128 rb:32 a:8 b:2 p:1

constexpr int   kNSites = 36;
constexpr int   kProj   = 51200;
constexpr float kEta    = 0.001f;

constexpr int G = 4;

// LDS layout (floats)
constexpr int OFF_HT   = 0;                    // hT[k*4+g], 256
constexpr int MS_SAMP  = 4352;                 // per-sample Ms: row0 64 | rows1-4 @64+(r-1)*1056 (u*66+d*4+l) | row5 @4288 (u*4+l)
constexpr int OFF_MS   = 256;                  // 4*4352 = 17408
constexpr int OFF_P    = OFF_MS + G*MS_SAMP;          // 17664, P[g*1024 + d*64+b*16+cc], 4096
constexpr int QT_S     = 1088;                 // Qt sample stride (64*17 rounded)
constexpr int QT_BUF   = G*QT_S;               // 4352
constexpr int OFF_QT   = OFF_P + G*1024;              // 21760, Qt[buf*4352 + g*1088 + ua*17 + cq], 8704
constexpr int MOLD_LS  = 260;                  // Mold[lb*260 + (u*16+cc)]
constexpr int OFF_MOLD = OFF_QT + 2*QT_BUF;           // 30464, 4160
constexpr int OFF_M2   = OFF_MOLD + 16*MOLD_LS;       // 34624, M2[ua*64 + cc*4+rb], 4096
constexpr int OFF_A2   = OFF_M2 + 4096;               // 38720, A2[g*256 + (l*4+b)*16 + a*4+rb], 1024
constexpr int OFF_VB   = OFF_A2 + G*256;              // 39744, vbuf[g*32 + pp*16 + e], 128
constexpr int LTOT     = OFF_VB + 128;                // 39872 floats = 159488 B

__global__ __launch_bounds__(512, 2)
void tn_amp(const int* __restrict__ x,
            const float* __restrict__ peps,
            const float* __restrict__ base_proj,
            const float* __restrict__ W1,
            const float* __restrict__ b1,
            const float* __restrict__ W2,
            const float* __restrict__ b2,
            float* __restrict__ out,
            int batch)
{
    __shared__ float L[LTOT];
    __shared__ int   xl[G * kNSites];

    const int tid   = threadIdx.x;
    const int sBase = blockIdx.x * G;

    // ---- stage x for 4 samples ----
    if (tid < G * kNSites) {
        int g  = tid / kNSites;
        int ii = tid - g * kNSites;
        int s  = sBase + g; if (s >= batch) s = batch - 1;
        xl[g * kNSites + ii] = x[s * kNSites + ii];
    }
    __syncthreads();

    // ---- h (packed hT[k][g]) + zero Ms ----
    if (tid < 256) {
        int g = tid >> 6, k = tid & 63;
        float acc = b1[k];
        for (int i = 0; i < kNSites; ++i)
            acc = fmaf((float)xl[g * kNSites + i], W1[i * 64 + k], acc);
        L[OFF_HT + k * 4 + g] = fmaxf(acc, 0.0f);
    }
    for (int i = tid; i < G * MS_SAMP; i += 512) L[OFF_MS + i] = 0.0f;
    __syncthreads();

    // ---- init boundary MPS from column 0 ----
    // logical Ms_r[u=a][d=b][l=rb] from peps[r,0,l=0,rb,a,b,p]
    for (int idx = tid; idx < 2048; idx += 512) {
        int g = idx >> 9, rr = (idx >> 6) & 7, u = (idx >> 4) & 3, d = (idx >> 2) & 3, l = idx & 3;
        if (rr >= 6) continue;
        int p = xl[g * kNSites + rr * 6 + 0];
        int msb = OFF_MS + g * MS_SAMP;
        if (rr == 0) {
            if (u == 0) L[msb + d * 4 + l] = peps[l * 32 + d * 2 + p];
        } else if (rr == 5) {
            if (d == 0) L[msb + 4288 + u * 4 + l] = peps[5 * 3072 + l * 32 + u * 8 + p];
        } else {
            L[msb + 64 + (rr - 1) * 1056 + u * 66 + d * 4 + l] =
                peps[rr * 3072 + l * 32 + u * 8 + d * 2 + p];
        }
    }
    __syncthreads();

    // ---- column sweep ----
    for (int c = 1; c < 6; ++c) {
        const int rb_dim = (c == 5) ? 1 : 4;
        for (int r = 0; r < 6; ++r) {
            // -- bond generation for (c-1, r), all 4 samples share W2 loads --
            if (r <= 4) {
                const int goff = ((c - 1) * 5 + r) << 11;
                const int jcol = tid << 2;                 // 0..2044
                float4 a0 = {0,0,0,0}, a1 = {0,0,0,0}, a2 = {0,0,0,0}, a3 = {0,0,0,0};
                const float* wptr = W2 + (size_t)goff + jcol;
#pragma unroll 8
                for (int k = 0; k < 64; ++k) {
                    float4 w  = *reinterpret_cast<const float4*>(wptr + (size_t)k * kProj);
                    float4 hv = *reinterpret_cast<float4*>(&L[OFF_HT + (k << 2)]);
                    a0.x = fmaf(w.x, hv.x, a0.x); a0.y = fmaf(w.y, hv.x, a0.y);
                    a0.z = fmaf(w.z, hv.x, a0.z); a0.w = fmaf(w.w, hv.x, a0.w);
                    a1.x = fmaf(w.x, hv.y, a1.x); a1.y = fmaf(w.y, hv.y, a1.y);
                    a1.z = fmaf(w.z, hv.y, a1.z); a1.w = fmaf(w.w, hv.y, a1.w);
                    a2.x = fmaf(w.x, hv.z, a2.x); a2.y = fmaf(w.y, hv.z, a2.y);
                    a2.z = fmaf(w.z, hv.z, a2.z); a2.w = fmaf(w.w, hv.z, a2.w);
                    a3.x = fmaf(w.x, hv.w, a3.x); a3.y = fmaf(w.y, hv.w, a3.y);
                    a3.z = fmaf(w.z, hv.w, a3.z); a3.w = fmaf(w.w, hv.w, a3.w);
                }
                float4 bp = *reinterpret_cast<const float4*>(base_proj + goff + jcol);
                float4 bb = *reinterpret_cast<const float4*>(b2 + goff + jcol);
                float4 v0, v1, v2, v3;
                v0.x = bp.x + kEta*(bb.x + a0.x); v0.y = bp.y + kEta*(bb.y + a0.y);
                v0.z = bp.z + kEta*(bb.z + a0.z); v0.w = bp.w + kEta*(bb.w + a0.w);
                v1.x = bp.x + kEta*(bb.x + a1.x); v1.y = bp.y + kEta*(bb.y + a1.y);
                v1.z = bp.z + kEta*(bb.z + a1.z); v1.w = bp.w + kEta*(bb.w + a1.w);
                v2.x = bp.x + kEta*(bb.x + a2.x); v2.y = bp.y + kEta*(bb.y + a2.y);
                v2.z = bp.z + kEta*(bb.z + a2.z); v2.w = bp.w + kEta*(bb.w + a2.w);
                v3.x = bp.x + kEta*(bb.x + a3.x); v3.y = bp.y + kEta*(bb.y + a3.y);
                v3.z = bp.z + kEta*(bb.z + a3.z); v3.w = bp.w + kEta*(bb.w + a3.w);
                if (jcol < 1024) {
                    *reinterpret_cast<float4*>(&L[OFF_P + 0*1024 + jcol]) = v0;
                    *reinterpret_cast<float4*>(&L[OFF_P + 1*1024 + jcol]) = v1;
                    *reinterpret_cast<float4*>(&L[OFF_P + 2*1024 + jcol]) = v2;
                    *reinterpret_cast<float4*>(&L[OFF_P + 3*1024 + jcol]) = v3;
                } else {
                    const int q = jcol - 1024, ua0 = q & 63, cq = q >> 6;
                    const int qb = OFF_QT + (r & 1) * QT_BUF + cq;
                    float* q0 = &L[qb + 0*QT_S + ua0*17];
                    float* q1 = &L[qb + 1*QT_S + ua0*17];
                    float* q2 = &L[qb + 2*QT_S + ua0*17];
                    float* q3 = &L[qb + 3*QT_S + ua0*17];
                    q0[0]=v0.x; q0[17]=v0.y; q0[34]=v0.z; q0[51]=v0.w;
                    q1[0]=v1.x; q1[17]=v1.y; q1[34]=v1.z; q1[51]=v1.w;
                    q2[0]=v2.x; q2[17]=v2.y; q2[34]=v2.z; q2[51]=v2.w;
                    q3[0]=v3.x; q3[17]=v3.y; q3[34]=v3.z; q3[51]=v3.w;
                }
            }
            // -- stage site tensors A2 for all samples --
            {
                const int adim = (r == 0) ? 1 : 4;
                const int bdim = (r == 5) ? 1 : 4;
                for (int idx = tid; idx < G * 256; idx += 512) {
                    int g = idx >> 8, rest = idx & 255;
                    int lb = rest >> 4, ar = rest & 15;
                    int l = lb >> 2, b = lb & 3, a = ar >> 2, rb = ar & 3;
                    float v = 0.0f;
                    if (a < adim && b < bdim && rb < rb_dim) {
                        int p = xl[g * kNSites + r * 6 + c];
                        v = peps[r * 3072 + c * 512 + l * 128 + rb * 32 + a * 8 + b * 2 + p];
                    }
                    L[OFF_A2 + idx] = v;
                }
            }
            __syncthreads();

            // -- phases, serial over samples --
            for (int g = 0; g < G; ++g) {
                const int msb0 = OFF_MS + g * MS_SAMP;
                if (r == 0) {
                    // p1: Mold[(0,cc)][lb] = sum_d Ms0[d,l] * P[d*64+b*16+cc]
                    if (tid < 256) {
                        int l = tid >> 6, b = (tid >> 4) & 3, cc = tid & 15;
                        float acc = 0.0f;
#pragma unroll
                        for (int d = 0; d < 16; ++d)
                            acc = fmaf(L[msb0 + d * 4 + l],
                                       L[OFF_P + (g << 10) + d * 64 + b * 16 + cc], acc);
                        L[OFF_MOLD + (l * 4 + b) * MOLD_LS + cc] = acc;
                    }
                    __syncthreads();
                    // p2 (ua=1): Ms0_new[cc,rb] = sum_lb Mold[cc][lb] * A2[lb][0*4+rb]
                    if (tid < 64) {
                        int cc = tid >> 2, rb = tid & 3;
                        float acc = 0.0f;
#pragma unroll
                        for (int lb = 0; lb < 16; ++lb)
                            acc = fmaf(L[OFF_MOLD + lb * MOLD_LS + cc],
                                       L[OFF_A2 + g * 256 + lb * 16 + rb], acc);
                        L[msb0 + cc * 4 + rb] = acc;
                    }
                    __syncthreads();
                } else if (r < 5) {
                    const int msb = msb0 + 64 + (r - 1) * 1056;
                    // p1: 4 matmuls (per l): [16x16]@[16x64]
                    if (tid < 256) {
                        int l = tid >> 6, ut = (tid >> 4) & 3, jt = tid & 15;
                        int b = jt >> 2, ccb = (jt & 3) * 4;
                        float4 acc[4] = {{0,0,0,0},{0,0,0,0},{0,0,0,0},{0,0,0,0}};
#pragma unroll
                        for (int d = 0; d < 16; ++d) {
                            float4 pv = *reinterpret_cast<float4*>(
                                &L[OFF_P + (g << 10) + d * 64 + (jt << 2)]);
#pragma unroll
                            for (int i = 0; i < 4; ++i) {
                                float m = L[msb + (ut + 4 * i) * 66 + d * 4 + l];
                                acc[i].x = fmaf(m, pv.x, acc[i].x);
                                acc[i].y = fmaf(m, pv.y, acc[i].y);
                                acc[i].z = fmaf(m, pv.z, acc[i].z);
                                acc[i].w = fmaf(m, pv.w, acc[i].w);
                            }
                        }
#pragma unroll
                        for (int i = 0; i < 4; ++i)
                            *reinterpret_cast<float4*>(
                                &L[OFF_MOLD + (l * 4 + b) * MOLD_LS + (ut + 4 * i) * 16 + ccb]) = acc[i];
                    }
                    __syncthreads();
                    // p2: [256x16]@[16x16]: M2[(u*4+a)][cc*4+rb] = sum_lb Mold[R][lb]*A2[lb][a*4+rb]
                    {
                        int rt = tid >> 2, at = tid & 3;
                        float4 acc0 = {0,0,0,0}, acc1 = {0,0,0,0};
#pragma unroll
                        for (int lb = 0; lb < 16; ++lb) {
                            float2 mo = *reinterpret_cast<float2*>(&L[OFF_MOLD + lb * MOLD_LS + rt * 2]);
                            float4 av = *reinterpret_cast<float4*>(&L[OFF_A2 + g * 256 + lb * 16 + at * 4]);
                            acc0.x = fmaf(mo.x, av.x, acc0.x); acc0.y = fmaf(mo.x, av.y, acc0.y);
                            acc0.z = fmaf(mo.x, av.z, acc0.z); acc0.w = fmaf(mo.x, av.w, acc0.w);
                            acc1.x = fmaf(mo.y, av.x, acc1.x); acc1.y = fmaf(mo.y, av.y, acc1.y);
                            acc1.z = fmaf(mo.y, av.z, acc1.z); acc1.w = fmaf(mo.y, av.w, acc1.w);
                        }
                        int R0 = rt * 2, u0 = R0 >> 4, cc0 = R0 & 15;
                        int R1 = R0 + 1, u1 = R1 >> 4, cc1 = R1 & 15;
                        *reinterpret_cast<float4*>(&L[OFF_M2 + (u0 * 4 + at) * 64 + cc0 * 4]) = acc0;
                        *reinterpret_cast<float4*>(&L[OFF_M2 + (u1 * 4 + at) * 64 + cc1 * 4]) = acc1;
                    }
                    __syncthreads();
                    // p3: Ms_new[cq][dn*4+rb] = sum_ua Qt[ua][cq] * M2[ua][dn*4+rb]
                    if (tid < 128) {
                        int cqt = tid >> 4, colt = tid & 15;
                        const int qb = OFF_QT + ((r & 1) ^ 1) * QT_BUF + g * QT_S + cqt * 2;
                        float4 acc0 = {0,0,0,0}, acc1 = {0,0,0,0};
#pragma unroll 8
                        for (int ua = 0; ua < 64; ++ua) {
                            float q0 = L[qb + ua * 17];
                            float q1 = L[qb + ua * 17 + 1];
                            float4 m = *reinterpret_cast<float4*>(&L[OFF_M2 + ua * 64 + colt * 4]);
                            acc0.x = fmaf(q0, m.x, acc0.x); acc0.y = fmaf(q0, m.y, acc0.y);
                            acc0.z = fmaf(q0, m.z, acc0.z); acc0.w = fmaf(q0, m.w, acc0.w);
                            acc1.x = fmaf(q1, m.x, acc1.x); acc1.y = fmaf(q1, m.y, acc1.y);
                            acc1.z = fmaf(q1, m.z, acc1.z); acc1.w = fmaf(q1, m.w, acc1.w);
                        }
                        int row0 = msb + (cqt * 2) * 66 + colt * 4;
                        int row1 = row0 + 66;
                        L[row0 + 0] = acc0.x; L[row0 + 1] = acc0.y;
                        L[row0 + 2] = acc0.z; L[row0 + 3] = acc0.w;
                        L[row1 + 0] = acc1.x; L[row1 + 1] = acc1.y;
                        L[row1 + 2] = acc1.z; L[row1 + 3] = acc1.w;
                    }
                    __syncthreads();
                } else { // r == 5
                    // p2': M2[ua][rb] = sum_l Ms5[u*4+l] * A2[(l*4)][a*4+rb]
                    if (tid < 256) {
                        int ua = tid >> 2, rb = tid & 3, u = ua >> 2, a = ua & 3;
                        float acc = 0.0f;
#pragma unroll
                        for (int l = 0; l < 4; ++l)
                            acc = fmaf(L[msb0 + 4288 + u * 4 + l],
                                       L[OFF_A2 + g * 256 + (l * 4) * 16 + a * 4 + rb], acc);
                        L[OFF_M2 + ua * 64 + rb] = acc;
                    }
                    __syncthreads();
                    // p3': Ms5_new[cq*4+rb] = sum_ua Qt[ua][cq] * M2[ua][rb]
                    if (tid < 64) {
                        int cq = tid >> 2, rb = tid & 3;
                        const int qb = OFF_QT + ((r & 1) ^ 1) * QT_BUF + g * QT_S + cq;
                        float acc = 0.0f;
#pragma unroll 8
                        for (int ua = 0; ua < 64; ++ua)
                            acc = fmaf(L[qb + ua * 17], L[OFF_M2 + ua * 64 + rb], acc);
                        L[msb0 + 4288 + cq * 4 + rb] = acc;
                    }
                    __syncthreads();
                }
            }
        }
    }

    // ---- final chain contraction (rb=0) ----
    if (tid < 64) {
        int g = tid >> 4, e = tid & 15;
        L[OFF_VB + g * 32 + e] = L[OFF_MS + g * MS_SAMP + e * 4];
    }
    __syncthreads();
    for (int rr = 1; rr < 5; ++rr) {
        if (tid < 64) {
            int g = tid >> 4, e = tid & 15;
            int pp = (rr - 1) & 1;
            const int msb = OFF_MS + g * MS_SAMP + 64 + (rr - 1) * 1056;
            float acc = 0.0f;
#pragma unroll
            for (int u = 0; u < 16; ++u)
                acc = fmaf(L[OFF_VB + g * 32 + pp * 16 + u], L[msb + u * 66 + e * 4], acc);
            L[OFF_VB + g * 32 + (rr & 1) * 16 + e] = acc;
        }
        __syncthreads();
    }
    if (tid < G) {
        int g = tid;
        if (sBase + g < batch) {
            float acc = 0.0f;
#pragma unroll
            for (int u = 0; u < 16; ++u)
                acc = fmaf(L[OFF_VB + g * 32 + u], L[OFF_MS + g * MS_SAMP + 4288 + u * 4], acc);
            out[sBase + g] = acc;
        }
    }
}

extern "C" void kernel_launch(void* const* d_in, const int* in_sizes, int n_in,
                              void* d_out, int out_size, void* d_ws, size_t ws_size,
                              hipStream_t stream) {
    const int*   x         = (const int*)d_in[0];
    const float* peps      = (const float*)d_in[1];
    const float* base_proj = (const float*)d_in[2];
    const float* W1        = (const float*)d_in[3];
    const float* b1        = (const float*)d_in[4];
    const float* W2        = (const float*)d_in[5];
    const float* b2        = (const float*)d_in[6];
    float*       out       = (float*)d_out;

    const int batch  = in_sizes[0] / kNSites;
    const int blocks = (batch + G - 1) / G;
    hipLaunchKernelGGL(tn_amp, dim3(blocks), dim3(512), 0, stream,
                       x, peps, base_proj, W1, b1, W2, b2, out, batch);
}